// Round 12
// baseline (88.965 us; speedup 1.0000x reference)
//
#include <hip/hip_runtime.h>
#include <math.h>

#define NODES 1024
#define BATCH 16
#define TLEN 24
#define LAYERS 24
#define NLANES (NODES * BATCH) /* 16384 */
#define LOG2E 1.44269504088896340736f

typedef float v2f __attribute__((ext_vector_type(2)));

#if __has_builtin(__builtin_amdgcn_rcpf)
__device__ __forceinline__ float fast_rcp(float x) { return __builtin_amdgcn_rcpf(x); }
#else
__device__ __forceinline__ float fast_rcp(float x) { return 1.0f / x; }
#endif

#if __has_builtin(__builtin_amdgcn_exp2f)
__device__ __forceinline__ float fast_exp2(float x) { return __builtin_amdgcn_exp2f(x); }
#else
__device__ __forceinline__ float fast_exp2(float x) { return exp2f(x); }
#endif

// Packed math via COMPILER vector ops (no inline asm) -> v_pk_* on gfx950.
#if __has_builtin(__builtin_elementwise_fma)
__device__ __forceinline__ v2f pk_fma(v2f a, v2f b, v2f c) {
    return __builtin_elementwise_fma(a, b, c);
}
#else
__device__ __forceinline__ v2f pk_fma(v2f a, v2f b, v2f c) {
    v2f d; d.x = fmaf(a.x, b.x, c.x); d.y = fmaf(a.y, b.y, c.y); return d;
}
#endif

struct GruK2 { v2f rW, rU, rC, zW, zU, zC, nW, nC, nU, nD; };

// Constants for ONE layer, duplicated into both packed halves (the two
// halves are two CHAINS of the same layer — weights shared).
__device__ __forceinline__ GruK2 make_kc(
    const float* __restrict__ w_ih, const float* __restrict__ w_hh,
    const float* __restrict__ b_ih, const float* __restrict__ b_hh, int l)
{
    GruK2 K;
    const float rW = -LOG2E * w_ih[l*3+0], rU = -LOG2E * w_hh[l*3+0];
    const float rC = -LOG2E * (b_ih[l*3+0] + b_hh[l*3+0]);
    const float zW = -LOG2E * w_ih[l*3+1], zU = -LOG2E * w_hh[l*3+1];
    const float zC = -LOG2E * (b_ih[l*3+1] + b_hh[l*3+1]);
    const float nW = -2.0f*LOG2E * w_ih[l*3+2], nC = -2.0f*LOG2E * b_ih[l*3+2];
    const float nU = -2.0f*LOG2E * w_hh[l*3+2], nD = -2.0f*LOG2E * b_hh[l*3+2];
    K.rW = (v2f){rW, rW}; K.rU = (v2f){rU, rU}; K.rC = (v2f){rC, rC};
    K.zW = (v2f){zW, zW}; K.zU = (v2f){zU, zU}; K.zC = (v2f){zC, zC};
    K.nW = (v2f){nW, nW}; K.nC = (v2f){nC, nC};
    K.nU = (v2f){nU, nU}; K.nD = (v2f){nD, nD};
    return K;
}

// GRU cell, v2f over 2 chains — arithmetic bit-identical to rounds 4-11:
// er/ez/en are e^{-a} forms; r = 1/(1+er);
// h' = (ez*(1-en) + h*(1+en)) / ((1+ez)*(1+en))  -- one final rcp.
__device__ __forceinline__ v2f gru_cell2(const GruK2& K, v2f h, v2f xin) {
    const v2f ONE = (v2f){1.0f, 1.0f};
    v2f ar = pk_fma(K.rU, h, pk_fma(K.rW, xin, K.rC));
    v2f az = pk_fma(K.zU, h, pk_fma(K.zW, xin, K.zC));
    v2f er; er.x = fast_exp2(ar.x); er.y = fast_exp2(ar.y);
    v2f ez; ez.x = fast_exp2(az.x); ez.y = fast_exp2(az.y);
    v2f er1 = er + ONE;
    v2f r;  r.x = fast_rcp(er1.x); r.y = fast_rcp(er1.y);
    v2f an = pk_fma(r, pk_fma(K.nU, h, K.nD), pk_fma(K.nW, xin, K.nC));
    v2f en; en.x = fast_exp2(an.x); en.y = fast_exp2(an.y);
    v2f num = pk_fma(en, h - ez, h + ez);
    v2f den = (ez + ONE) * (en + ONE);
    v2f rd; rd.x = fast_rcp(den.x); rd.y = fast_rcp(den.y);
    return num * rd;
}

// Ring-pipelined GRU: 24-lane rings (r4 geometry), ONE layer per lane,
// TWO CHAINS packed per lane (v2f). Wave64 = 2 rings (lanes 0-23, 32-55;
// never crossing the 32-lane half). 4 chains/wave -> 4096 waves = 4/SIMD
// (most TLP of any measured config) with fully packed VALU (least issue
// per cell). Round-12 = r4 + the overhead fixes proven in r5-r9:
// fill/steady/drain split (no per-tick masks in the 168 steady ticks) and
// SW-pipelined ring handoff (rel computed at end of tick k, used in k+1).
__global__ __launch_bounds__(256, 4) void gru_pipe_kernel(
    const float* __restrict__ inputs, const float* __restrict__ w_ih,
    const float* __restrict__ w_hh, const float* __restrict__ b_ih,
    const float* __restrict__ b_hh, const int* __restrict__ horizon_p,
    float* __restrict__ hv, float* __restrict__ h_out)
{
    __shared__ v2f xp[8][TLEN];          // per chain-PAIR input seq, packed
    const int tid = threadIdx.x;
    const int wid = tid >> 6;
    const int lane = tid & 63;
    const int grp = lane & 32;           // ring group: 0 or 32
    const int l = lane & 31;             // layer if < 24
    const bool is_layer = (l < LAYERS);
    const int half = lane >> 5;
    const int pairidx = wid * 2 + half;  // 0..7 within block
    const int c0 = blockIdx.x * 16 + pairidx * 2;   // chains c0, c0+1

    const GruK2 K = make_kc(w_ih, w_hh, b_ih, b_hh, is_layer ? l : 0);

    // Stage 16 chains' input seqs as pairs: xp[p][t] = {x_{2p}[t], x_{2p+1}[t]}
    for (int i = tid; i < 16 * TLEN; i += 256) {
        const int cl = i / TLEN, t = i - cl * TLEN;
        const int cc = blockIdx.x * 16 + cl;
        const int node = cc >> 4, b = cc & 15;
        ((float*)xp)[(cl >> 1) * (TLEN * 2) + t * 2 + (cl & 1)] =
            inputs[((size_t)b * NODES + node) * TLEN + t];
    }
    __syncthreads();

    const int H = *horizon_p;
    const int last = H * TLEN;                        // 192 for H=8
    const int srcl = is_layer ? ((l == 0) ? (LAYERS - 1) : (l - 1)) : l;
    const int ringsrc = grp | srcl;                   // prev lane in 24-ring
    const bool lead = is_layer && (l == 0);
    const v2f* xrow = &xp[pairidx][0];

    v2f h = (v2f){0.0f, 0.0f};
    v2f rel = (v2f){0.0f, 0.0f};  // == shfl(h after tick k-1); h init 0

    // Fill: ticks [0, 24). Lead lane takes the original input pair.
    for (int k = 0; k < TLEN; ++k) {
        v2f xf = xrow[k];
        v2f in;
        in.x = lead ? xf.x : rel.x;
        in.y = lead ? xf.y : rel.y;
        v2f hn = gru_cell2(K, h, in);
        const bool act = is_layer && (k >= l);
        h.x = act ? hn.x : h.x;
        h.y = act ? hn.y : h.y;
        rel.x = __shfl(h.x, ringsrc, 64);             // for tick k+1
        rel.y = __shfl(h.y, ringsrc, 64);
    }
    // Steady: ticks [24, last) — every ring lane active, NO masks, no
    // lead special-case (pass-wrap 0<-23 is the same shfl). Idle lanes
    // (l>=24) self-shfl and iterate bounded values — harmless.
    #pragma unroll 8
    for (int k = TLEN; k < last; ++k) {
        h = gru_cell2(K, h, rel);
        rel.x = __shfl(h.x, ringsrc, 64);
        rel.y = __shfl(h.y, ringsrc, 64);
    }
    // Drain: ticks [last, last+23). Lane l's final update is tick l+last-1.
    for (int k = last; k < last + LAYERS - 1; ++k) {
        v2f hn = gru_cell2(K, h, rel);
        const bool act = (k < l + last);
        h.x = act ? hn.x : h.x;
        h.y = act ? hn.y : h.y;
        rel.x = __shfl(h.x, ringsrc, 64);
        rel.y = __shfl(h.y, ringsrc, 64);
    }

    if (is_layer) {
        // hv[l][c0..c0+1] (8B store) and h_out[node][l][b..b+1] (b even)
        *(v2f*)(hv + (size_t)l * NLANES + c0) = h;
        const int node = c0 >> 4, b = c0 & 15;
        *(v2f*)(h_out + (size_t)node * (LAYERS * BATCH) + l * BATCH + b) = h;
    }
}

// adj[l][i][j] = dot_b(hv[l,i,:], hv[l,j,:]) * inv_i * inv_j.
// 64x64 tile per 256-thread block; B tile transposed in LDS (conflict-free).
// At the HBM-write floor (~100 MB output at ~6.5 TB/s measured, ~16 us).
__global__ __launch_bounds__(256) void adj_kernel(
    const float* __restrict__ hv, float* __restrict__ adj)
{
    const int l = blockIdx.z;
    const int i0 = blockIdx.y * 64;
    const int j0 = blockIdx.x * 64;
    __shared__ float As[64 * 16];   // [row][k]
    __shared__ float Bt[16 * 64];   // [k][col]
    __shared__ float iA[64];
    __shared__ float iB[64];
    const int tid = threadIdx.x;
    const float* hvl = hv + (size_t)l * NLANES;

    ((float4*)As)[tid] = ((const float4*)(hvl + (size_t)i0 * 16))[tid];
    {
        const int j = tid >> 2;
        const int kc = (tid & 3) * 4;
        float4 bv = *(const float4*)(hvl + (size_t)(j0 + j) * 16 + kc);
        Bt[(kc + 0) * 64 + j] = bv.x;
        Bt[(kc + 1) * 64 + j] = bv.y;
        Bt[(kc + 2) * 64 + j] = bv.z;
        Bt[(kc + 3) * 64 + j] = bv.w;
    }
    __syncthreads();

    if (tid < 64) {
        float s = 0.0f;
        #pragma unroll
        for (int k = 0; k < 16; ++k) { float v = As[tid * 16 + k]; s = fmaf(v, v, s); }
        iA[tid] = fast_rcp(fmaxf(sqrtf(s), 1e-8f));
    } else if (tid < 128) {
        const int j = tid - 64;
        float s = 0.0f;
        #pragma unroll
        for (int k = 0; k < 16; ++k) { float v = Bt[k * 64 + j]; s = fmaf(v, v, s); }
        iB[j] = fast_rcp(fmaxf(sqrtf(s), 1e-8f));
    }
    __syncthreads();

    const int ty = tid >> 4;   // row group (4 rows)
    const int tx = tid & 15;   // col group (4 cols = 1 float4)

    float4 acc0 = {0,0,0,0}, acc1 = {0,0,0,0}, acc2 = {0,0,0,0}, acc3 = {0,0,0,0};
    #pragma unroll
    for (int kk = 0; kk < 4; ++kk) {
        float4 a0 = ((const float4*)As)[(ty * 4 + 0) * 4 + kk];
        float4 a1 = ((const float4*)As)[(ty * 4 + 1) * 4 + kk];
        float4 a2 = ((const float4*)As)[(ty * 4 + 2) * 4 + kk];
        float4 a3 = ((const float4*)As)[(ty * 4 + 3) * 4 + kk];
        #pragma unroll
        for (int e = 0; e < 4; ++e) {
            const int k = kk * 4 + e;
            float4 bk = ((const float4*)Bt)[k * 16 + tx];
            const float a0e = (e == 0) ? a0.x : (e == 1) ? a0.y : (e == 2) ? a0.z : a0.w;
            const float a1e = (e == 0) ? a1.x : (e == 1) ? a1.y : (e == 2) ? a1.z : a1.w;
            const float a2e = (e == 0) ? a2.x : (e == 1) ? a2.y : (e == 2) ? a2.z : a2.w;
            const float a3e = (e == 0) ? a3.x : (e == 1) ? a3.y : (e == 2) ? a3.z : a3.w;
            acc0.x = fmaf(a0e, bk.x, acc0.x); acc0.y = fmaf(a0e, bk.y, acc0.y);
            acc0.z = fmaf(a0e, bk.z, acc0.z); acc0.w = fmaf(a0e, bk.w, acc0.w);
            acc1.x = fmaf(a1e, bk.x, acc1.x); acc1.y = fmaf(a1e, bk.y, acc1.y);
            acc1.z = fmaf(a1e, bk.z, acc1.z); acc1.w = fmaf(a1e, bk.w, acc1.w);
            acc2.x = fmaf(a2e, bk.x, acc2.x); acc2.y = fmaf(a2e, bk.y, acc2.y);
            acc2.z = fmaf(a2e, bk.z, acc2.z); acc2.w = fmaf(a2e, bk.w, acc2.w);
            acc3.x = fmaf(a3e, bk.x, acc3.x); acc3.y = fmaf(a3e, bk.y, acc3.y);
            acc3.z = fmaf(a3e, bk.z, acc3.z); acc3.w = fmaf(a3e, bk.w, acc3.w);
        }
    }

    float* out = adj + (size_t)l * NODES * NODES;
    const float4 ib4 = ((const float4*)iB)[tx];
    #pragma unroll
    for (int ii = 0; ii < 4; ++ii) {
        const int i = i0 + ty * 4 + ii;
        const float si = iA[ty * 4 + ii];
        float4 a = (ii == 0) ? acc0 : (ii == 1) ? acc1 : (ii == 2) ? acc2 : acc3;
        float4 w;
        w.x = a.x * si * ib4.x;
        w.y = a.y * si * ib4.y;
        w.z = a.z * si * ib4.z;
        w.w = a.w * si * ib4.w;
        *(float4*)(out + (size_t)i * NODES + j0 + tx * 4) = w;
    }
}

extern "C" void kernel_launch(void* const* d_in, const int* in_sizes, int n_in,
                              void* d_out, int out_size, void* d_ws, size_t ws_size,
                              hipStream_t stream) {
    const float* inputs = (const float*)d_in[0];
    const float* w_ih   = (const float*)d_in[1];
    const float* w_hh   = (const float*)d_in[2];
    const float* b_ih   = (const float*)d_in[3];
    const float* b_hh   = (const float*)d_in[4];
    const int*   horiz  = (const int*)d_in[5];

    float* adj   = (float*)d_out;                                   // [24,1024,1024]
    float* h_out = (float*)d_out + (size_t)LAYERS * NODES * NODES;  // [1024,24,16]
    float* hv    = (float*)d_ws;                                    // [24][16384]

    // 1024 blocks x 256 threads = 4096 waves = 4/SIMD; 16 chains/block
    gru_pipe_kernel<<<NLANES / 16, 256, 0, stream>>>(inputs, w_ih, w_hh, b_ih, b_hh,
                                                     horiz, hv, h_out);

    dim3 grid(NODES / 64, NODES / 64, LAYERS);
    adj_kernel<<<grid, 256, 0, stream>>>(hv, adj);
}

// Round 13
// 76.085 us; speedup vs baseline: 1.1693x; 1.1693x over previous
//
#include <hip/hip_runtime.h>
#include <math.h>

#define NODES 1024
#define BATCH 16
#define TLEN 24
#define LAYERS 24
#define NLANES (NODES * BATCH) /* 16384 */
#define LOG2E 1.44269504088896340736f

typedef float v2f __attribute__((ext_vector_type(2)));

#if __has_builtin(__builtin_amdgcn_rcpf)
__device__ __forceinline__ float fast_rcp(float x) { return __builtin_amdgcn_rcpf(x); }
#else
__device__ __forceinline__ float fast_rcp(float x) { return 1.0f / x; }
#endif

#if __has_builtin(__builtin_amdgcn_exp2f)
__device__ __forceinline__ float fast_exp2(float x) { return __builtin_amdgcn_exp2f(x); }
#else
__device__ __forceinline__ float fast_exp2(float x) { return exp2f(x); }
#endif

#if __has_builtin(__builtin_elementwise_fma)
__device__ __forceinline__ v2f pk_fma(v2f a, v2f b, v2f c) {
    return __builtin_elementwise_fma(a, b, c);
}
#else
__device__ __forceinline__ v2f pk_fma(v2f a, v2f b, v2f c) {
    v2f d; d.x = fmaf(a.x, b.x, c.x); d.y = fmaf(a.y, b.y, c.y); return d;
}
#endif

struct GruK2 { v2f rW, rU, rC, zW, zU, zC, nW, nC, nU, nD; };
struct GruKs { float rW, rU, rC, zW, zU, zC, nW, nC, nU, nD; };

__device__ __forceinline__ GruK2 make_k2(
    const float* __restrict__ w_ih, const float* __restrict__ w_hh,
    const float* __restrict__ b_ih, const float* __restrict__ b_hh,
    int la, int lb)
{
    GruK2 K;
    #pragma unroll
    for (int s = 0; s < 2; ++s) {
        const int l = s ? lb : la;
        K.rW[s] = -LOG2E * w_ih[l*3+0]; K.rU[s] = -LOG2E * w_hh[l*3+0];
        K.rC[s] = -LOG2E * (b_ih[l*3+0] + b_hh[l*3+0]);
        K.zW[s] = -LOG2E * w_ih[l*3+1]; K.zU[s] = -LOG2E * w_hh[l*3+1];
        K.zC[s] = -LOG2E * (b_ih[l*3+1] + b_hh[l*3+1]);
        K.nW[s] = -2.0f*LOG2E * w_ih[l*3+2]; K.nC[s] = -2.0f*LOG2E * b_ih[l*3+2];
        K.nU[s] = -2.0f*LOG2E * w_hh[l*3+2]; K.nD[s] = -2.0f*LOG2E * b_hh[l*3+2];
    }
    return K;
}

__device__ __forceinline__ GruKs make_ks(
    const float* __restrict__ w_ih, const float* __restrict__ w_hh,
    const float* __restrict__ b_ih, const float* __restrict__ b_hh, int l)
{
    GruKs K;
    K.rW = -LOG2E * w_ih[l*3+0]; K.rU = -LOG2E * w_hh[l*3+0];
    K.rC = -LOG2E * (b_ih[l*3+0] + b_hh[l*3+0]);
    K.zW = -LOG2E * w_ih[l*3+1]; K.zU = -LOG2E * w_hh[l*3+1];
    K.zC = -LOG2E * (b_ih[l*3+1] + b_hh[l*3+1]);
    K.nW = -2.0f*LOG2E * w_ih[l*3+2]; K.nC = -2.0f*LOG2E * b_ih[l*3+2];
    K.nU = -2.0f*LOG2E * w_hh[l*3+2]; K.nD = -2.0f*LOG2E * b_hh[l*3+2];
    return K;
}

// Fused, PHASE-INTERLEAVED triple cell: layers (L0,L0+1) as v2f h01 and
// layer L0+2 as scalar h2, computed together with all same-kind trans ops
// batched per phase (A: gate args, B: 6x exp2, C: 3x rcp, D: an + 3x exp2,
// E: finals). Per-component arithmetic bit-identical to rounds 4-12:
// er/ez/en are e^{-a} forms; r = 1/(1+er);
// h' = (ez*(1-en) + h*(1+en)) / ((1+ez)*(1+en)).
__device__ __forceinline__ void tri_cell(
    const GruK2& K01, const GruKs& K2, v2f h01, float h2, float rel,
    v2f& n01, float& n2)
{
    const v2f ONE = (v2f){1.0f, 1.0f};
    v2f in01; in01.x = rel; in01.y = h01.x;
    const float in2 = h01.y;
    // Phase A — all gate arguments (h2 path first)
    float ar2 = fmaf(K2.rU, h2, fmaf(K2.rW, in2, K2.rC));
    float az2 = fmaf(K2.zU, h2, fmaf(K2.zW, in2, K2.zC));
    v2f ar01 = pk_fma(K01.rU, h01, pk_fma(K01.rW, in01, K01.rC));
    v2f az01 = pk_fma(K01.zU, h01, pk_fma(K01.zW, in01, K01.zC));
    // Phase B — 6 exp2 back-to-back (each latency hidden by siblings' issue)
    float er2 = fast_exp2(ar2);
    float ez2 = fast_exp2(az2);
    v2f er01; er01.x = fast_exp2(ar01.x); er01.y = fast_exp2(ar01.y);
    v2f ez01; ez01.x = fast_exp2(az01.x); ez01.y = fast_exp2(az01.y);
    // Phase C — 3 r-gate rcp
    float r2 = fast_rcp(1.0f + er2);
    v2f e1 = er01 + ONE;
    v2f r01; r01.x = fast_rcp(e1.x); r01.y = fast_rcp(e1.y);
    // Phase D — n-gate args + 3 exp2
    float an2 = fmaf(r2, fmaf(K2.nU, h2, K2.nD), fmaf(K2.nW, in2, K2.nC));
    v2f an01 = pk_fma(r01, pk_fma(K01.nU, h01, K01.nD), pk_fma(K01.nW, in01, K01.nC));
    float en2 = fast_exp2(an2);
    v2f en01; en01.x = fast_exp2(an01.x); en01.y = fast_exp2(an01.y);
    // Phase E — finals (h2 first so its consumer/shfl can issue early)
    float num2 = fmaf(en2, h2 - ez2, h2 + ez2);
    float den2 = (1.0f + ez2) * (1.0f + en2);
    n2 = num2 * fast_rcp(den2);
    v2f num01 = pk_fma(en01, h01 - ez01, h01 + ez01);
    v2f den01 = (ez01 + ONE) * (en01 + ONE);
    v2f rd; rd.x = fast_rcp(den01.x); rd.y = fast_rcp(den01.y);
    n01 = num01 * rd;
}

// Ring-pipelined GRU: 8-lane rings, 3 CONSECUTIVE layers per lane, ONE chain
// per lane, SW-pipelined ring handoff (r9 structure, bit-identical math).
// Round-13 change: the per-tick body is the hand-fused phase-interleaved
// tri_cell, forcing the cross-cell instruction interleave the scheduler
// declined to produce (r9-r10: VGPR stayed 32, cells serialized, ~150
// exposed trans-latency cyc/wave-tick).
__global__ __launch_bounds__(256, 2) void gru_pipe_kernel(
    const float* __restrict__ inputs, const float* __restrict__ w_ih,
    const float* __restrict__ w_hh, const float* __restrict__ b_ih,
    const float* __restrict__ b_hh, const int* __restrict__ horizon_p,
    float* __restrict__ hv, float* __restrict__ h_out)
{
    __shared__ float xl[32][TLEN + 1];   // 32 chains/block, +1 pad
    const int tid = threadIdx.x;
    const int wid = tid >> 6;
    const int lane = tid & 63;
    const int ring = lane >> 3;          // 0..7
    const int sl = lane & 7;             // ring-local lane
    const int L0 = 3 * sl;               // first owned layer
    const int chain_local = wid * 8 + ring;
    const int c = blockIdx.x * 32 + chain_local;

    const GruK2 K01 = make_k2(w_ih, w_hh, b_ih, b_hh, L0, L0 + 1);
    const GruKs K2  = make_ks(w_ih, w_hh, b_ih, b_hh, L0 + 2);

    for (int i = tid; i < 32 * TLEN; i += 256) {
        const int cl = i / TLEN, t = i - cl * TLEN;
        const int cc = blockIdx.x * 32 + cl;
        const int node = cc >> 4, b = cc & 15;
        xl[cl][t] = inputs[((size_t)b * NODES + node) * TLEN + t];
    }
    __syncthreads();

    const int H = *horizon_p;
    const int last = H * TLEN;                        // 192 for H=8
    const int ringsrc = (lane & 56) | ((sl + 7) & 7); // prev lane in 8-ring
    const bool lead = (sl == 0);
    const float* xrow = &xl[chain_local][0];

    v2f h01 = (v2f){0.0f, 0.0f};
    float h2 = 0.0f;
    float rel = 0.0f;   // == shfl(h2 after tick k-1); h2 init 0 -> rel 0

    // Fill: ticks [0, 24). Lead lane's first slot takes the original input.
    for (int k = 0; k < TLEN; ++k) {
        float inA = lead ? xrow[k] : rel;
        v2f n01; float n2;
        tri_cell(K01, K2, h01, h2, inA, n01, n2);
        h01.x = (k >= L0 + 0) ? n01.x : h01.x;
        h01.y = (k >= L0 + 1) ? n01.y : h01.y;
        h2    = (k >= L0 + 2) ? n2   : h2;
        rel = __shfl(h2, ringsrc, 64);               // for tick k+1
    }
    // Steady: ticks [24, last) — no masks. Fused body inline with the shfl
    // issued as soon as the new h2 is ready (before h01's final phase).
    #pragma unroll 8
    for (int k = TLEN; k < last; ++k) {
        const v2f ONE = (v2f){1.0f, 1.0f};
        v2f in01; in01.x = rel; in01.y = h01.x;
        const float in2 = h01.y;
        // A
        float ar2 = fmaf(K2.rU, h2, fmaf(K2.rW, in2, K2.rC));
        float az2 = fmaf(K2.zU, h2, fmaf(K2.zW, in2, K2.zC));
        v2f ar01 = pk_fma(K01.rU, h01, pk_fma(K01.rW, in01, K01.rC));
        v2f az01 = pk_fma(K01.zU, h01, pk_fma(K01.zW, in01, K01.zC));
        // B
        float er2 = fast_exp2(ar2);
        float ez2 = fast_exp2(az2);
        v2f er01; er01.x = fast_exp2(ar01.x); er01.y = fast_exp2(ar01.y);
        v2f ez01; ez01.x = fast_exp2(az01.x); ez01.y = fast_exp2(az01.y);
        // C
        float r2 = fast_rcp(1.0f + er2);
        v2f e1 = er01 + ONE;
        v2f r01; r01.x = fast_rcp(e1.x); r01.y = fast_rcp(e1.y);
        // D
        float an2 = fmaf(r2, fmaf(K2.nU, h2, K2.nD), fmaf(K2.nW, in2, K2.nC));
        v2f an01 = pk_fma(r01, pk_fma(K01.nU, h01, K01.nD), pk_fma(K01.nW, in01, K01.nC));
        float en2 = fast_exp2(an2);
        v2f en01; en01.x = fast_exp2(an01.x); en01.y = fast_exp2(an01.y);
        // E — h2 finishes first; shfl issues under h01's tail
        float num2 = fmaf(en2, h2 - ez2, h2 + ez2);
        float den2 = (1.0f + ez2) * (1.0f + en2);
        h2 = num2 * fast_rcp(den2);
        rel = __shfl(h2, ringsrc, 64);
        v2f num01 = pk_fma(en01, h01 - ez01, h01 + ez01);
        v2f den01 = (ez01 + ONE) * (en01 + ONE);
        v2f rd; rd.x = fast_rcp(den01.x); rd.y = fast_rcp(den01.y);
        h01 = num01 * rd;
    }
    // Drain: ticks [last, last+23). Layer l's last update is tick l+last-1.
    for (int k = last; k < last + LAYERS - 1; ++k) {
        v2f n01; float n2;
        tri_cell(K01, K2, h01, h2, rel, n01, n2);
        h01.x = (k < L0 + 0 + last) ? n01.x : h01.x;
        h01.y = (k < L0 + 1 + last) ? n01.y : h01.y;
        h2    = (k < L0 + 2 + last) ? n2   : h2;
        rel = __shfl(h2, ringsrc, 64);
    }

    // Outputs: hv[L][c] scratch and h_out[node][L][b].
    const int node = c >> 4, b = c & 15;
    float* ho = h_out + (size_t)node * (LAYERS * BATCH) + b;
    hv[(size_t)(L0 + 0) * NLANES + c] = h01.x;  ho[(L0 + 0) * BATCH] = h01.x;
    hv[(size_t)(L0 + 1) * NLANES + c] = h01.y;  ho[(L0 + 1) * BATCH] = h01.y;
    hv[(size_t)(L0 + 2) * NLANES + c] = h2;     ho[(L0 + 2) * BATCH] = h2;
}

// adj[l][i][j] = dot_b(hv[l,i,:], hv[l,j,:]) * inv_i * inv_j.
// 64x64 tile per 256-thread block; B tile transposed in LDS (conflict-free).
// At the HBM-write floor (~100 MB output at ~6.5 TB/s measured, ~16 us).
__global__ __launch_bounds__(256) void adj_kernel(
    const float* __restrict__ hv, float* __restrict__ adj)
{
    const int l = blockIdx.z;
    const int i0 = blockIdx.y * 64;
    const int j0 = blockIdx.x * 64;
    __shared__ float As[64 * 16];   // [row][k]
    __shared__ float Bt[16 * 64];   // [k][col]
    __shared__ float iA[64];
    __shared__ float iB[64];
    const int tid = threadIdx.x;
    const float* hvl = hv + (size_t)l * NLANES;

    ((float4*)As)[tid] = ((const float4*)(hvl + (size_t)i0 * 16))[tid];
    {
        const int j = tid >> 2;
        const int kc = (tid & 3) * 4;
        float4 bv = *(const float4*)(hvl + (size_t)(j0 + j) * 16 + kc);
        Bt[(kc + 0) * 64 + j] = bv.x;
        Bt[(kc + 1) * 64 + j] = bv.y;
        Bt[(kc + 2) * 64 + j] = bv.z;
        Bt[(kc + 3) * 64 + j] = bv.w;
    }
    __syncthreads();

    if (tid < 64) {
        float s = 0.0f;
        #pragma unroll
        for (int k = 0; k < 16; ++k) { float v = As[tid * 16 + k]; s = fmaf(v, v, s); }
        iA[tid] = fast_rcp(fmaxf(sqrtf(s), 1e-8f));
    } else if (tid < 128) {
        const int j = tid - 64;
        float s = 0.0f;
        #pragma unroll
        for (int k = 0; k < 16; ++k) { float v = Bt[k * 64 + j]; s = fmaf(v, v, s); }
        iB[j] = fast_rcp(fmaxf(sqrtf(s), 1e-8f));
    }
    __syncthreads();

    const int ty = tid >> 4;   // row group (4 rows)
    const int tx = tid & 15;   // col group (4 cols = 1 float4)

    float4 acc0 = {0,0,0,0}, acc1 = {0,0,0,0}, acc2 = {0,0,0,0}, acc3 = {0,0,0,0};
    #pragma unroll
    for (int kk = 0; kk < 4; ++kk) {
        float4 a0 = ((const float4*)As)[(ty * 4 + 0) * 4 + kk];
        float4 a1 = ((const float4*)As)[(ty * 4 + 1) * 4 + kk];
        float4 a2 = ((const float4*)As)[(ty * 4 + 2) * 4 + kk];
        float4 a3 = ((const float4*)As)[(ty * 4 + 3) * 4 + kk];
        #pragma unroll
        for (int e = 0; e < 4; ++e) {
            const int k = kk * 4 + e;
            float4 bk = ((const float4*)Bt)[k * 16 + tx];
            const float a0e = (e == 0) ? a0.x : (e == 1) ? a0.y : (e == 2) ? a0.z : a0.w;
            const float a1e = (e == 0) ? a1.x : (e == 1) ? a1.y : (e == 2) ? a1.z : a1.w;
            const float a2e = (e == 0) ? a2.x : (e == 1) ? a2.y : (e == 2) ? a2.z : a2.w;
            const float a3e = (e == 0) ? a3.x : (e == 1) ? a3.y : (e == 2) ? a3.z : a3.w;
            acc0.x = fmaf(a0e, bk.x, acc0.x); acc0.y = fmaf(a0e, bk.y, acc0.y);
            acc0.z = fmaf(a0e, bk.z, acc0.z); acc0.w = fmaf(a0e, bk.w, acc0.w);
            acc1.x = fmaf(a1e, bk.x, acc1.x); acc1.y = fmaf(a1e, bk.y, acc1.y);
            acc1.z = fmaf(a1e, bk.z, acc1.z); acc1.w = fmaf(a1e, bk.w, acc1.w);
            acc2.x = fmaf(a2e, bk.x, acc2.x); acc2.y = fmaf(a2e, bk.y, acc2.y);
            acc2.z = fmaf(a2e, bk.z, acc2.z); acc2.w = fmaf(a2e, bk.w, acc2.w);
            acc3.x = fmaf(a3e, bk.x, acc3.x); acc3.y = fmaf(a3e, bk.y, acc3.y);
            acc3.z = fmaf(a3e, bk.z, acc3.z); acc3.w = fmaf(a3e, bk.w, acc3.w);
        }
    }

    float* out = adj + (size_t)l * NODES * NODES;
    const float4 ib4 = ((const float4*)iB)[tx];
    #pragma unroll
    for (int ii = 0; ii < 4; ++ii) {
        const int i = i0 + ty * 4 + ii;
        const float si = iA[ty * 4 + ii];
        float4 a = (ii == 0) ? acc0 : (ii == 1) ? acc1 : (ii == 2) ? acc2 : acc3;
        float4 w;
        w.x = a.x * si * ib4.x;
        w.y = a.y * si * ib4.y;
        w.z = a.z * si * ib4.z;
        w.w = a.w * si * ib4.w;
        *(float4*)(out + (size_t)i * NODES + j0 + tx * 4) = w;
    }
}

extern "C" void kernel_launch(void* const* d_in, const int* in_sizes, int n_in,
                              void* d_out, int out_size, void* d_ws, size_t ws_size,
                              hipStream_t stream) {
    const float* inputs = (const float*)d_in[0];
    const float* w_ih   = (const float*)d_in[1];
    const float* w_hh   = (const float*)d_in[2];
    const float* b_ih   = (const float*)d_in[3];
    const float* b_hh   = (const float*)d_in[4];
    const int*   horiz  = (const int*)d_in[5];

    float* adj   = (float*)d_out;                                   // [24,1024,1024]
    float* h_out = (float*)d_out + (size_t)LAYERS * NODES * NODES;  // [1024,24,16]
    float* hv    = (float*)d_ws;                                    // [24][16384]

    // 512 blocks x 256 threads = 2048 waves = 2/SIMD; 32 chains/block
    gru_pipe_kernel<<<NLANES / 32, 256, 0, stream>>>(inputs, w_ih, w_hh, b_ih, b_hh,
                                                     horiz, hv, h_out);

    dim3 grid(NODES / 64, NODES / 64, LAYERS);
    adj_kernel<<<grid, 256, 0, stream>>>(hv, adj);
}